// Round 15
// baseline (178.754 us; speedup 1.0000x reference)
//
#include <hip/hip_runtime.h>
#include <cstddef>
#include <cstdint>

// Problem constants: B=2, S=2048, E=1024, H=16, DK=64
constexpr size_t OUT_ELEMS = (size_t)2 * 2048 * 1024;   // 4,194,304

typedef _Float16 f16_t;
typedef __attribute__((ext_vector_type(8))) _Float16 f16x8;
typedef __attribute__((ext_vector_type(4))) float f32x4;

#define SCL2      0.1803368801111204f    // 0.125 * log2(e): logits in log2 domain
#define LOG2_0P1  -3.3219280948873623f   // log2(0.1)

#define EXP2F(x)  __builtin_amdgcn_exp2f(x)
#define LOG2F(x)  __builtin_amdgcn_logf(x)

__device__ __forceinline__ f32x4 mfma16(f16x8 a, f16x8 b, f32x4 c) {
    return __builtin_amdgcn_mfma_f32_16x16x32_f16(a, b, c, 0, 0, 0);
}

__device__ __forceinline__ void gload16(const void* g, void* l) {
    __builtin_amdgcn_global_load_lds(
        (const __attribute__((address_space(1))) void*)g,
        (__attribute__((address_space(3))) void*)l, 16, 0, 0);
}

// ---------------------------------------------------------------------------
// Input prep: all 7 tensors -> plain f16.  grid (4096, 7).
// ---------------------------------------------------------------------------
__global__ __launch_bounds__(256)
void prep_kernel(const float4* __restrict__ q, const float4* __restrict__ k,
                 const float4* __restrict__ v, const float4* __restrict__ wq,
                 const float4* __restrict__ wk, const float4* __restrict__ wv,
                 const float4* __restrict__ wp,
                 unsigned short* __restrict__ xq, unsigned short* __restrict__ xk,
                 unsigned short* __restrict__ xv, unsigned short* __restrict__ wqh,
                 unsigned short* __restrict__ wkh, unsigned short* __restrict__ wvh,
                 unsigned short* __restrict__ wph)
{
    const int z = blockIdx.y;
    const int i = blockIdx.x * 256 + threadIdx.x;
    const float4* src; unsigned short* dst; int total4;
    switch (z) {
        case 0:  src = q;  dst = xq;  total4 = 1048576; break;
        case 1:  src = k;  dst = xk;  total4 = 1048576; break;
        case 2:  src = v;  dst = xv;  total4 = 1048576; break;
        case 3:  src = wq; dst = wqh; total4 = 262144;  break;
        case 4:  src = wk; dst = wkh; total4 = 262144;  break;
        case 5:  src = wv; dst = wvh; total4 = 262144;  break;
        default: src = wp; dst = wph; total4 = 262144;  break;
    }
    if (i >= total4) return;
    const float4 v4 = src[i];
    const float vv[4] = {v4.x, v4.y, v4.z, v4.w};
    unsigned short u[4];
#pragma unroll
    for (int j = 0; j < 4; ++j) {
        f16_t h = (f16_t)vv[j];
        u[j] = __builtin_bit_cast(unsigned short, h);
    }
    uint2 w;
    w.x = u[0] | ((unsigned)u[1] << 16); w.y = u[2] | ((unsigned)u[3] << 16);
    *(uint2*)(dst + (size_t)i * 4) = w;
}

// ---------------------------------------------------------------------------
// MFMA GEMM: 128x128 tile, BK=64, 512 thr.  T3-minimum 2-phase: 2 LDS
// buffers (64 KB -> 2 blocks/CU), stage(next) BEFORE compute(cur), one
// __syncthreads per iter (its vmcnt drain lands after compute covered the
// load latency).  WAR-safe: buf (ki+1)&1 written while ki&1 read; a buffer
// is only overwritten after the barrier where all waves finished reading it.
// OUTMODE: 0 = Q/K f16 [bh][s][64] (x scaleB) + raw f32 (grid.z selects the
//              operand set when two are passed); 1 = vT f16; 2 = f32 out.
// OUTMODE 2: clean M-tiles (no dirty merged rows) write out = bias and exit.
// ---------------------------------------------------------------------------
template<int OUTMODE>
__global__ __launch_bounds__(512)
void gemm_mfma(const f16_t* __restrict__ A, const f16_t* __restrict__ B,
               const float* __restrict__ bias, float scaleB,
               float* __restrict__ outF, f16_t* __restrict__ outB,
               const unsigned* __restrict__ dmask,
               const f16_t* A2 = nullptr, const f16_t* B2 = nullptr,
               const float* bias2 = nullptr, float scaleB2 = 1.0f,
               float* outF2 = nullptr, f16_t* outB2 = nullptr)
{
    __shared__ __align__(16) char Asl[2][16384];
    __shared__ __align__(16) char Bsl[2][16384];

    const int tid = threadIdx.x;
    const int lane = tid & 63;
    const int w = tid >> 6;
    const int wm = w >> 1;
    const int wn = w & 1;
    const int n0 = blockIdx.x * 128;
    const int m0 = blockIdx.y * 128;

    if (OUTMODE == 0 && blockIdx.z == 1) {
        A = A2; B = B2; bias = bias2; scaleB = scaleB2; outF = outF2; outB = outB2;
    }

    if (OUTMODE == 2) {
        const int bb = m0 >> 11;
        const int st0 = (m0 & 2047) >> 6;
        unsigned dd = 0;
        for (int hh = 0; hh < 16; ++hh)
            dd |= dmask[(bb * 16 + hh) * 32 + st0] | dmask[(bb * 16 + hh) * 32 + st0 + 1];
        if (dd == 0u) {
            const int row = tid >> 2;
            const int c0 = (tid & 3) * 32;
            float* dst = outF + (size_t)(m0 + row) * 1024 + n0 + c0;
#pragma unroll
            for (int j = 0; j < 8; ++j)
                *(float4*)(dst + j * 4) = *(const float4*)(bias + n0 + c0 + j * 4);
            return;
        }
    }

    f32x4 acc[2][4] = {};

    auto stage = [&](int ki, int buf) {
        const int kt = ki * 64;
#pragma unroll
        for (int inst = 0; inst < 2; ++inst) {
            int L = inst * 8192 + tid * 16;
            int row = L >> 7;
            int k16 = ((L >> 4) & 7) ^ (row & 7);
            gload16(A + (size_t)(m0 + row) * 1024 + kt + k16 * 8,
                    Asl[buf] + inst * 8192 + w * 1024);
            gload16(B + (size_t)(n0 + row) * 1024 + kt + k16 * 8,
                    Bsl[buf] + inst * 8192 + w * 1024);
        }
    };

    stage(0, 0);
    __syncthreads();

    for (int ki = 0; ki < 16; ++ki) {
        if (ki + 1 < 16) stage(ki + 1, (ki + 1) & 1);   // loads fly during compute
        const char* Ab = Asl[ki & 1];
        const char* Bb = Bsl[ki & 1];
#pragma unroll
        for (int kf = 0; kf < 2; ++kf) {
            const int k16 = kf * 4 + (lane >> 4);
            f16x8 af[2], bfr[4];
#pragma unroll
            for (int mi = 0; mi < 2; ++mi) {
                int row = wm * 32 + mi * 16 + (lane & 15);
                af[mi] = *(const f16x8*)(Ab + (row << 7) + ((k16 ^ (row & 7)) << 4));
            }
#pragma unroll
            for (int ni = 0; ni < 4; ++ni) {
                int row = wn * 64 + ni * 16 + (lane & 15);
                bfr[ni] = *(const f16x8*)(Bb + (row << 7) + ((k16 ^ (row & 7)) << 4));
            }
#pragma unroll
            for (int mi = 0; mi < 2; ++mi)
#pragma unroll
                for (int ni = 0; ni < 4; ++ni)
                    acc[mi][ni] = mfma16(af[mi], bfr[ni], acc[mi][ni]);
        }
        if (ki + 1 < 16) __syncthreads();   // next buf ready; cur buf free
    }

    const int crow0 = wm * 32 + (lane >> 4) * 4;
    const int ccol0 = wn * 64 + (lane & 15);
#pragma unroll
    for (int mi = 0; mi < 2; ++mi) {
#pragma unroll
        for (int ni = 0; ni < 4; ++ni) {
            const int n = n0 + ccol0 + ni * 16;
            const float bb = bias[n];
            if (OUTMODE == 2) {
#pragma unroll
                for (int r = 0; r < 4; ++r) {
                    const int m = m0 + crow0 + mi * 16 + r;
                    outF[(size_t)m * 1024 + n] = acc[mi][ni][r] + bb;
                }
            } else if (OUTMODE == 0) {
                const int h = n >> 6, d = n & 63;
#pragma unroll
                for (int r = 0; r < 4; ++r) {
                    const int m = m0 + crow0 + mi * 16 + r;
                    const int b = m >> 11, s = m & 2047;
                    const float v = acc[mi][ni][r] + bb;
                    const size_t idx = ((size_t)(b * 16 + h) * 2048 + s) * 64 + d;
                    outB[idx] = (f16_t)(v * scaleB);
                    outF[idx] = v;
                }
            } else {
                const int h = n >> 6, d = n & 63;
                const int m = m0 + crow0 + mi * 16;
                const int b = m >> 11, s = m & 2047;
                unsigned short us[4];
#pragma unroll
                for (int r = 0; r < 4; ++r) {
                    f16_t t = (f16_t)(acc[mi][ni][r] + bb);
                    us[r] = __builtin_bit_cast(unsigned short, t);
                }
                uint2 pk;
                pk.x = us[0] | ((unsigned)us[1] << 16);
                pk.y = us[2] | ((unsigned)us[3] << 16);
                *(uint2*)(outB + ((size_t)(b * 16 + h) * 64 + d) * 2048 + s) = pk;
            }
        }
    }
}

// ---------------------------------------------------------------------------
// Z-sweep (r12, proven 41.6 us): K-stationary, one barrier total.
// Grid (16 tc, 32 bh), 512 thr.  partials[bh][s][tc16] = (sum exp2, max).
// ---------------------------------------------------------------------------
__global__ __launch_bounds__(512)
void attn_zsweep_kernel(const f16_t* __restrict__ qh, const f16_t* __restrict__ kh,
                        float2* __restrict__ partials)
{
    __shared__ __align__(16) char Klds[16384];   // [128 t][64 d] f16 swizzled

    const int tid = threadIdx.x;
    const int lane = tid & 63;
    const int g = lane >> 4;
    const int w = tid >> 6;
    const int tc = blockIdx.x;
    const int bh = blockIdx.y;

    {
        const size_t kbase = ((size_t)bh * 2048 + tc * 128) * 64;
#pragma unroll
        for (int inst = 0; inst < 2; ++inst) {
            int L = inst * 8192 + tid * 16;
            int row = L >> 7;
            int k16 = ((L >> 4) & 7) ^ (row & 7);
            gload16(kh + kbase + (size_t)row * 64 + k16 * 8,
                    Klds + inst * 8192 + w * 1024);
        }
    }
    __syncthreads();   // only barrier in the kernel

    auto qload = [&](int si, f16x8& a, f16x8& b) {
        const size_t rb = ((size_t)bh * 2048 + si * 128 + w * 16 + (lane & 15)) * 64;
        a = *(const f16x8*)(qh + rb + g * 8);
        b = *(const f16x8*)(qh + rb + 32 + g * 8);
    };

    auto compute = [&](int si, f16x8 q0, f16x8 q1) {
        f32x4 acc[8] = {};
#pragma unroll
        for (int kf = 0; kf < 2; ++kf) {
            const f16x8 qf = kf ? q1 : q0;
            const int k16 = kf * 4 + g;
#pragma unroll
            for (int tg = 0; tg < 8; ++tg) {
                const int t = tg * 16 + (lane & 15);
                f16x8 bfr = *(const f16x8*)(Klds + (t << 7) + ((k16 ^ (t & 7)) << 4));
                acc[tg] = mfma16(qf, bfr, acc[tg]);
            }
        }
#pragma unroll
        for (int r = 0; r < 4; ++r) {
            float sm = 0.0f, mx = -1e30f;
#pragma unroll
            for (int tg = 0; tg < 8; ++tg) {
                const float l2 = acc[tg][r];
                sm += EXP2F(l2);
                mx = fmaxf(mx, l2);
            }
#pragma unroll
            for (int mk = 1; mk < 16; mk <<= 1) {
                sm += __shfl_xor(sm, mk);
                mx = fmaxf(mx, __shfl_xor(mx, mk));
            }
            if ((lane & 15) == 0) {
                const int srow = si * 128 + w * 16 + g * 4 + r;
                partials[((size_t)bh * 2048 + srow) * 16 + tc] = make_float2(sm, mx);
            }
        }
    };

    f16x8 qA0, qA1, qB0, qB1;
    qload(0, qA0, qA1);
    for (int si = 0; si < 16; si += 2) {
        qload(si + 1, qB0, qB1);
        compute(si, qA0, qA1);
        if (si + 2 < 16) qload(si + 2, qA0, qA1);
        compute(si + 1, qB0, qB1);
    }
}

// ---------------------------------------------------------------------------
// Z-reduce (r12): partials(16) -> lgZ + per-(bh, 64-row stile) dirty mask.
// ---------------------------------------------------------------------------
__global__ __launch_bounds__(256)
void zred_kernel(const float2* __restrict__ partials, float* __restrict__ stats,
                 unsigned* __restrict__ dirtymask)
{
    const int tid = threadIdx.x;
    const int bh = blockIdx.y;
    const int s = blockIdx.x * 256 + tid;
    const float4* p = (const float4*)(partials + ((size_t)bh * 2048 + s) * 16);
    float sm = 0.0f, mx = -1e30f;
#pragma unroll
    for (int i = 0; i < 8; ++i) {
        const float4 v = p[i];
        sm += v.x + v.z;
        mx = fmaxf(mx, fmaxf(v.y, v.w));
    }
    const float lgZ = LOG2F(sm);
    stats[(size_t)bh * 2048 + s] = lgZ;
    const bool dirty = mx > lgZ + LOG2_0P1 - 0.10f;
    const unsigned long long m = __ballot(dirty);
    if ((tid & 63) == 0)
        dirtymask[bh * 32 + (s >> 6)] = (m != 0ull) ? 1u : 0u;
}

// ---------------------------------------------------------------------------
// PV (r12): clean -> zero-fill merged slice; dirty (rare) -> chunk-flagged
// re-sweep with exact p + fp32 boundary arbitration + PV MFMA.
// ---------------------------------------------------------------------------
__global__ __launch_bounds__(256)
void attn_pv_kernel(const f16_t* __restrict__ qh, const f16_t* __restrict__ kh,
                    const f16_t* __restrict__ vT,
                    const float* __restrict__ qf32, const float* __restrict__ kf32,
                    const float* __restrict__ stats, const unsigned* __restrict__ dirtymask,
                    const float2* __restrict__ partials,
                    f16_t* __restrict__ merged)
{
    __shared__ __align__(16) char Klds[8192];
    __shared__ __align__(16) char Vlds[8192];
    __shared__ __align__(16) char Pl[4][2048];
    __shared__ unsigned cflags;

    const int tid = threadIdx.x;
    const int lane = tid & 63;
    const int g = lane >> 4;
    const int w = tid >> 6;
    const int s0 = blockIdx.x * 64;
    const int bh = blockIdx.y;
    const int b = bh >> 4, h = bh & 15;

    if (dirtymask[bh * 32 + blockIdx.x] == 0u) {
        const int row = s0 + (tid >> 2);
        f16_t* dst = merged + ((size_t)b * 2048 + row) * 1024 + h * 64 + (tid & 3) * 16;
        const uint4 z = {0u, 0u, 0u, 0u};
        *(uint4*)dst = z;
        *(uint4*)(dst + 8) = z;
        return;
    }

    // ---- rare dirty path ----
    f16x8 qf[2];
    float lgZ[4], lthr[4];
    {
        const size_t rowbase = ((size_t)bh * 2048 + s0 + w * 16 + (lane & 15)) * 64;
        qf[0] = *(const f16x8*)(qh + rowbase + g * 8);
        qf[1] = *(const f16x8*)(qh + rowbase + 32 + g * 8);
#pragma unroll
        for (int r = 0; r < 4; ++r) {
            lgZ[r] = stats[(size_t)bh * 2048 + s0 + w * 16 + g * 4 + r];
            lthr[r] = lgZ[r] + LOG2_0P1;
        }
    }

    // chunk-survivor flags from partials (per-row 128-t chunk maxima)
    if (tid == 0) cflags = 0u;
    __syncthreads();
    {
        unsigned f = 0;
#pragma unroll
        for (int r = 0; r < 4; ++r) {
            const size_t rowg = (size_t)bh * 2048 + s0 + w * 16 + g * 4 + r;
            const float thr = lthr[r] - 0.10f;
#pragma unroll
            for (int tc = 0; tc < 16; ++tc)
                if (partials[rowg * 16 + tc].y > thr) f |= (1u << tc);
        }
        if (f) atomicOr(&cflags, f);
    }
    __syncthreads();
    const unsigned flags = cflags;

    const size_t kbase = (size_t)bh * 2048 * 64;
    const size_t vbase = (size_t)bh * 64 * 2048;

    f32x4 hacc[4] = {};
    for (int tcc = 0; tcc < 2048; tcc += 64) {
        if (!((flags >> (tcc >> 7)) & 1u)) continue;   // block-uniform skip
#pragma unroll
        for (int inst = 0; inst < 2; ++inst) {
            int L = inst * 4096 + tid * 16;
            int t = L >> 7;
            int k16 = ((L >> 4) & 7) ^ (t & 7);
            gload16(kh + kbase + (size_t)(tcc + t) * 64 + k16 * 8,
                    Klds + inst * 4096 + w * 1024);
            int d = t;
            gload16(vT + vbase + (size_t)d * 2048 + tcc + k16 * 8,
                    Vlds + inst * 4096 + w * 1024);
        }
        __syncthreads();

        f32x4 acc[4] = {};
#pragma unroll
        for (int kf = 0; kf < 2; ++kf) {
            const int k16 = kf * 4 + g;
            f16x8 bfr[4];
#pragma unroll
            for (int tg = 0; tg < 4; ++tg) {
                int t = tg * 16 + (lane & 15);
                bfr[tg] = *(const f16x8*)(Klds + (t << 7) + ((k16 ^ (t & 7)) << 4));
            }
#pragma unroll
            for (int tg = 0; tg < 4; ++tg)
                acc[tg] = mfma16(qf[kf], bfr[tg], acc[tg]);
        }

        char* pb = Pl[w];
        bool any = false;
#pragma unroll
        for (int tg = 0; tg < 4; ++tg)
#pragma unroll
            for (int r = 0; r < 4; ++r) {
                const float l2 = acc[tg][r];
                float p = 0.0f;
                if (l2 > lthr[r] - 0.07f) {
                    if (fabsf(l2 - lthr[r]) < 0.07f) {
                        const float* qr = qf32 + ((size_t)bh * 2048 + s0 + w * 16 + g * 4 + r) * 64;
                        const float* kr = kf32 + ((size_t)bh * 2048 + tcc + tg * 16 + (lane & 15)) * 64;
                        float dt = 0.0f;
                        for (int dd = 0; dd < 64; ++dd) dt += qr[dd] * kr[dd];
                        const float pe = EXP2F(dt * SCL2 - lgZ[r]);
                        p = (pe > 0.1f) ? pe : 0.0f;
                    } else {
                        p = EXP2F(l2 - lgZ[r]);
                    }
                }
                any |= (p != 0.0f);
                const int row = g * 4 + r;
                const int t = tg * 16 + (lane & 15);
                *(f16_t*)(pb + (row << 7) + ((2 * t) ^ ((row & 7) << 4))) = (f16_t)p;
            }

        if (__ballot(any) != 0ull) {
#pragma unroll
            for (int kf = 0; kf < 2; ++kf) {
                const int t16 = kf * 4 + g;
                f16x8 pa, vb[4];
                {
                    const int row = lane & 15;
                    pa = *(const f16x8*)(pb + (row << 7) + ((t16 ^ (row & 7)) << 4));
                }
#pragma unroll
                for (int ni = 0; ni < 4; ++ni) {
                    const int d = ni * 16 + (lane & 15);
                    vb[ni] = *(const f16x8*)(Vlds + (d << 7) + ((t16 ^ (d & 7)) << 4));
                }
#pragma unroll
                for (int ni = 0; ni < 4; ++ni)
                    hacc[ni] = mfma16(pa, vb[ni], hacc[ni]);
            }
        }
        __syncthreads();
    }

#pragma unroll
    for (int ni = 0; ni < 4; ++ni)
#pragma unroll
        for (int r = 0; r < 4; ++r) {
            const int srow = s0 + w * 16 + g * 4 + r;
            const int col = h * 64 + ni * 16 + (lane & 15);
            merged[((size_t)b * 2048 + srow) * 1024 + col] = (f16_t)hacc[ni][r];
        }
}

// ---------------------------------------------------------------------------
// Adjacency (r12, proven 41.6 us): grid (16 tc128, 32 sc64, 2 b), 256 thr,
// 2-buf __syncthreads K schedule + Q register ping-pong, LB(256,4).
// ---------------------------------------------------------------------------
__global__ __launch_bounds__(256, 4)
void attn_adj_kernel(const f16_t* __restrict__ qh, const f16_t* __restrict__ kh,
                     const float* __restrict__ stats, float* __restrict__ adj)
{
    __shared__ __align__(16) char Klds[2][16384];  // [128 t][64 d] f16 swizzled
    __shared__ __align__(16) float Sl[16 * 64];    // [16 h][64 s] lgZ

    const int tid = threadIdx.x;
    const int lane = tid & 63;
    const int g = lane >> 4;
    const int w = tid >> 6;
    const int t0 = blockIdx.x * 128;
    const int s0 = blockIdx.y * 64;
    const int b  = blockIdx.z;

    // stage all 16 heads' stats via plain loads (covered by first barrier)
    {
        const int hh = tid >> 4;
        const int sl = (tid * 4) & 63;
        const float4 v = *(const float4*)(stats + ((size_t)(b * 16 + hh) * 2048 + s0 + sl));
        *(float4*)&Sl[tid * 4] = v;
    }

    auto stageK = [&](int h, int buf) {
        const size_t kbase = ((size_t)(b * 16 + h) * 2048 + t0) * 64;
#pragma unroll
        for (int inst = 0; inst < 4; ++inst) {
            int L = inst * 4096 + tid * 16;
            int row = L >> 7;
            int k16 = ((L >> 4) & 7) ^ (row & 7);
            gload16(kh + kbase + (size_t)row * 64 + k16 * 8,
                    Klds[buf] + inst * 4096 + w * 1024);
        }
    };
    auto qload = [&](int h, f16x8& a, f16x8& bq) {
        const size_t rb = ((size_t)(b * 16 + h) * 2048 + s0 + w * 16 + (lane & 15)) * 64;
        a  = *(const f16x8*)(qh + rb + g * 8);
        bq = *(const f16x8*)(qh + rb + 32 + g * 8);
    };

    f32x4 aacc[8] = {};

    auto body = [&](int h, f16x8 q0, f16x8 q1) {
        float cc[4];
#pragma unroll
        for (int r = 0; r < 4; ++r)
            cc[r] = Sl[h * 64 + w * 16 + g * 4 + r] + 4.0f;   // +4: fold mean_h
        const char* Kb = Klds[h & 1];
        f32x4 acc[8] = {};
#pragma unroll
        for (int kf = 0; kf < 2; ++kf) {
            const f16x8 qf = kf ? q1 : q0;
            const int k16 = kf * 4 + g;
#pragma unroll
            for (int tg = 0; tg < 8; ++tg) {
                const int t = tg * 16 + (lane & 15);
                const f16x8 bfr = *(const f16x8*)(Kb + (t << 7) + ((k16 ^ (t & 7)) << 4));
                acc[tg] = mfma16(qf, bfr, acc[tg]);
            }
        }
#pragma unroll
        for (int tg = 0; tg < 8; ++tg)
#pragma unroll
            for (int r = 0; r < 4; ++r)
                aacc[tg][r] += EXP2F(acc[tg][r] - cc[r]);
    };

    f16x8 qA0, qA1, qB0, qB1;
    stageK(0, 0);
    qload(0, qA0, qA1);
    __syncthreads();   // buf0 + stats ready (drains q0 loads too)

    for (int h = 0; h < 16; h += 2) {
        if (h + 1 < 16) { stageK(h + 1, (h + 1) & 1); qload(h + 1, qB0, qB1); }
        body(h, qA0, qA1);
        __syncthreads();
        if (h + 2 < 16) { stageK(h + 2, (h + 2) & 1); qload(h + 2, qA0, qA1); }
        body(h + 1, qB0, qB1);
        __syncthreads();
    }

#pragma unroll
    for (int tg = 0; tg < 8; ++tg)
#pragma unroll
        for (int r = 0; r < 4; ++r) {
            const int s = s0 + w * 16 + g * 4 + r;
            adj[((size_t)b * 2048 + s) * 2048 + t0 + tg * 16 + (lane & 15)] = aacc[tg][r];
        }
}

// ---------------------------------------------------------------------------
extern "C" void kernel_launch(void* const* d_in, const int* in_sizes, int n_in,
                              void* d_out, int out_size, void* d_ws, size_t ws_size,
                              hipStream_t stream)
{
    (void)in_sizes; (void)n_in; (void)out_size; (void)ws_size;

    const float* queries = (const float*)d_in[0];
    const float* keys    = (const float*)d_in[1];
    const float* values  = (const float*)d_in[2];
    const float* Wq = (const float*)d_in[3];
    const float* bq = (const float*)d_in[4];
    const float* Wk = (const float*)d_in[5];
    const float* bk = (const float*)d_in[6];
    const float* Wv = (const float*)d_in[7];
    const float* bv = (const float*)d_in[8];
    const float* Wp = (const float*)d_in[9];
    const float* bp = (const float*)d_in[10];

    float* out = (float*)d_out;
    float* adj = out + OUT_ELEMS;

    // workspace layout (bytes).  partials/dirtymask overlay Xq/Xv (dead
    // after the projection GEMMs).
    char* ws = (char*)d_ws;
    f16_t* Xq   = (f16_t*)(ws);                    // [4096][1024] f16   8.39 MB
    f16_t* Xk   = (f16_t*)(ws + 8388608);
    f16_t* Xv   = (f16_t*)(ws + 16777216);
    f16_t* Wqh  = (f16_t*)(ws + 25165824);         // [1024][1024] f16
    f16_t* Wkh  = (f16_t*)(ws + 27262976);
    f16_t* Wvh  = (f16_t*)(ws + 29360128);
    f16_t* Wph  = (f16_t*)(ws + 31457280);
    f16_t* qh16 = (f16_t*)(ws + 33554432);         // [32][2048][64] f16
    f16_t* kh16 = (f16_t*)(ws + 41943040);
    f16_t* vT   = (f16_t*)(ws + 50331648);         // [32][64][2048] f16
    f16_t* mg   = (f16_t*)(ws + 58720256);         // [4096][1024] f16
    float* qf32 = (float*)(ws + 67108864);         // [32][2048][64] f32
    float* kf32 = (float*)(ws + 83886080);
    float* stats = (float*)(ws + 100663296);       // [32][2048] lgZ
    float2* partials  = (float2*)(ws);             // [32][2048][16] f2 = 8.4 MB (overlays Xq)
    unsigned* dirtymask = (unsigned*)(ws + 16777216 + 4194304);  // inside dead Xv

    prep_kernel<<<dim3(4096, 7), 256, 0, stream>>>(
        (const float4*)queries, (const float4*)keys, (const float4*)values,
        (const float4*)Wq, (const float4*)Wk, (const float4*)Wv, (const float4*)Wp,
        (unsigned short*)Xq, (unsigned short*)Xk, (unsigned short*)Xv,
        (unsigned short*)Wqh, (unsigned short*)Wkh, (unsigned short*)Wvh,
        (unsigned short*)Wph);

    // Q and K projections in ONE launch (grid.z selects operand set)
    gemm_mfma<0><<<dim3(8, 32, 2), 512, 0, stream>>>(
        Xq, Wqh, bq, SCL2, qf32, qh16, nullptr,
        Xk, Wkh, bk, 1.0f, kf32, kh16);
    gemm_mfma<1><<<dim3(8, 32), 512, 0, stream>>>(Xv, Wvh, bv, 1.0f, nullptr, vT, nullptr);

    attn_zsweep_kernel<<<dim3(16, 32), 512, 0, stream>>>(qh16, kh16, partials);
    zred_kernel<<<dim3(8, 32), 256, 0, stream>>>(partials, stats, dirtymask);
    attn_pv_kernel<<<dim3(32, 32), 256, 0, stream>>>(qh16, kh16, vT, qf32, kf32,
                                                     stats, dirtymask, partials, mg);
    attn_adj_kernel<<<dim3(16, 32, 2), 256, 0, stream>>>(qh16, kh16, stats, adj);

    gemm_mfma<2><<<dim3(8, 32), 512, 0, stream>>>(mg, Wph, bp, 1.0f, out, nullptr, dirtymask);
}

// Round 16
// 175.696 us; speedup vs baseline: 1.0174x; 1.0174x over previous
//
#include <hip/hip_runtime.h>
#include <cstddef>
#include <cstdint>

// Problem constants: B=2, S=2048, E=1024, H=16, DK=64
constexpr size_t OUT_ELEMS = (size_t)2 * 2048 * 1024;   // 4,194,304

typedef _Float16 f16_t;
typedef __attribute__((ext_vector_type(8))) _Float16 f16x8;
typedef __attribute__((ext_vector_type(4))) float f32x4;

#define SCL2      0.1803368801111204f    // 0.125 * log2(e): logits in log2 domain
#define LOG2_0P1  -3.3219280948873623f   // log2(0.1)

#define EXP2F(x)  __builtin_amdgcn_exp2f(x)
#define LOG2F(x)  __builtin_amdgcn_logf(x)

#define WAITV(N)  asm volatile("s_waitcnt vmcnt(" #N ")" ::: "memory")
__device__ __forceinline__ void ringbar() {
    __builtin_amdgcn_s_barrier();
    __builtin_amdgcn_sched_barrier(0);
}

__device__ __forceinline__ f32x4 mfma16(f16x8 a, f16x8 b, f32x4 c) {
    return __builtin_amdgcn_mfma_f32_16x16x32_f16(a, b, c, 0, 0, 0);
}

__device__ __forceinline__ void gload16(const void* g, void* l) {
    __builtin_amdgcn_global_load_lds(
        (const __attribute__((address_space(1))) void*)g,
        (__attribute__((address_space(3))) void*)l, 16, 0, 0);
}

// ---------------------------------------------------------------------------
// Input prep: all 7 tensors -> plain f16.  grid (4096, 7).
// ---------------------------------------------------------------------------
__global__ __launch_bounds__(256)
void prep_kernel(const float4* __restrict__ q, const float4* __restrict__ k,
                 const float4* __restrict__ v, const float4* __restrict__ wq,
                 const float4* __restrict__ wk, const float4* __restrict__ wv,
                 const float4* __restrict__ wp,
                 unsigned short* __restrict__ xq, unsigned short* __restrict__ xk,
                 unsigned short* __restrict__ xv, unsigned short* __restrict__ wqh,
                 unsigned short* __restrict__ wkh, unsigned short* __restrict__ wvh,
                 unsigned short* __restrict__ wph)
{
    const int z = blockIdx.y;
    const int i = blockIdx.x * 256 + threadIdx.x;
    const float4* src; unsigned short* dst; int total4;
    switch (z) {
        case 0:  src = q;  dst = xq;  total4 = 1048576; break;
        case 1:  src = k;  dst = xk;  total4 = 1048576; break;
        case 2:  src = v;  dst = xv;  total4 = 1048576; break;
        case 3:  src = wq; dst = wqh; total4 = 262144;  break;
        case 4:  src = wk; dst = wkh; total4 = 262144;  break;
        case 5:  src = wv; dst = wvh; total4 = 262144;  break;
        default: src = wp; dst = wph; total4 = 262144;  break;
    }
    if (i >= total4) return;
    const float4 v4 = src[i];
    const float vv[4] = {v4.x, v4.y, v4.z, v4.w};
    unsigned short u[4];
#pragma unroll
    for (int j = 0; j < 4; ++j) {
        f16_t h = (f16_t)vv[j];
        u[j] = __builtin_bit_cast(unsigned short, h);
    }
    uint2 w;
    w.x = u[0] | ((unsigned)u[1] << 16); w.y = u[2] | ((unsigned)u[3] << 16);
    *(uint2*)(dst + (size_t)i * 4) = w;
}

// ---------------------------------------------------------------------------
// MFMA GEMM (r12, proven): 128x128 tile, BK=64, 512 thr, NB=3 ring, counted
// vmcnt(4) (pure-gload16 FIFO -> counted waits sound).
// OUTMODE: 0 = Q/K f16 [bh][s][64] (x scaleB) + raw f32; 1 = vT f16; 2 = f32.
// OUTMODE 2: clean M-tiles (no dirty merged rows) write out = bias and exit.
// ---------------------------------------------------------------------------
template<int OUTMODE>
__global__ __launch_bounds__(512)
void gemm_mfma(const f16_t* __restrict__ A, const f16_t* __restrict__ B,
               const float* __restrict__ bias, float scaleB,
               float* __restrict__ outF, f16_t* __restrict__ outB,
               const unsigned* __restrict__ dmask)
{
    __shared__ __align__(16) char Asl[3][16384];
    __shared__ __align__(16) char Bsl[3][16384];

    const int tid = threadIdx.x;
    const int lane = tid & 63;
    const int w = tid >> 6;
    const int wm = w >> 1;
    const int wn = w & 1;
    const int n0 = blockIdx.x * 128;
    const int m0 = blockIdx.y * 128;

    if (OUTMODE == 2) {
        const int bb = m0 >> 11;
        const int st0 = (m0 & 2047) >> 6;
        unsigned dd = 0;
        for (int hh = 0; hh < 16; ++hh)
            dd |= dmask[(bb * 16 + hh) * 32 + st0] | dmask[(bb * 16 + hh) * 32 + st0 + 1];
        if (dd == 0u) {
            const int row = tid >> 2;
            const int c0 = (tid & 3) * 32;
            float* dst = outF + (size_t)(m0 + row) * 1024 + n0 + c0;
#pragma unroll
            for (int j = 0; j < 8; ++j)
                *(float4*)(dst + j * 4) = *(const float4*)(bias + n0 + c0 + j * 4);
            return;
        }
    }

    f32x4 acc[2][4] = {};

    auto stage = [&](int ki, int buf) {
        const int kt = ki * 64;
#pragma unroll
        for (int inst = 0; inst < 2; ++inst) {
            int L = inst * 8192 + tid * 16;
            int row = L >> 7;
            int k16 = ((L >> 4) & 7) ^ (row & 7);
            gload16(A + (size_t)(m0 + row) * 1024 + kt + k16 * 8,
                    Asl[buf] + inst * 8192 + w * 1024);
            gload16(B + (size_t)(n0 + row) * 1024 + kt + k16 * 8,
                    Bsl[buf] + inst * 8192 + w * 1024);
        }
    };

    stage(0, 0);

    for (int ki = 0; ki < 16; ++ki) {
        if (ki + 1 < 16) stage(ki + 1, (ki + 1) % 3);
        if (ki < 15) { WAITV(4); } else { WAITV(0); }
        ringbar();
        const char* Ab = Asl[ki % 3];
        const char* Bb = Bsl[ki % 3];
#pragma unroll
        for (int kf = 0; kf < 2; ++kf) {
            const int k16 = kf * 4 + (lane >> 4);
            f16x8 af[2], bfr[4];
#pragma unroll
            for (int mi = 0; mi < 2; ++mi) {
                int row = wm * 32 + mi * 16 + (lane & 15);
                af[mi] = *(const f16x8*)(Ab + (row << 7) + ((k16 ^ (row & 7)) << 4));
            }
#pragma unroll
            for (int ni = 0; ni < 4; ++ni) {
                int row = wn * 64 + ni * 16 + (lane & 15);
                bfr[ni] = *(const f16x8*)(Bb + (row << 7) + ((k16 ^ (row & 7)) << 4));
            }
#pragma unroll
            for (int mi = 0; mi < 2; ++mi)
#pragma unroll
                for (int ni = 0; ni < 4; ++ni)
                    acc[mi][ni] = mfma16(af[mi], bfr[ni], acc[mi][ni]);
        }
    }

    const int crow0 = wm * 32 + (lane >> 4) * 4;
    const int ccol0 = wn * 64 + (lane & 15);
#pragma unroll
    for (int mi = 0; mi < 2; ++mi) {
#pragma unroll
        for (int ni = 0; ni < 4; ++ni) {
            const int n = n0 + ccol0 + ni * 16;
            const float bb = bias[n];
            if (OUTMODE == 2) {
#pragma unroll
                for (int r = 0; r < 4; ++r) {
                    const int m = m0 + crow0 + mi * 16 + r;
                    outF[(size_t)m * 1024 + n] = acc[mi][ni][r] + bb;
                }
            } else if (OUTMODE == 0) {
                const int h = n >> 6, d = n & 63;
#pragma unroll
                for (int r = 0; r < 4; ++r) {
                    const int m = m0 + crow0 + mi * 16 + r;
                    const int b = m >> 11, s = m & 2047;
                    const float v = acc[mi][ni][r] + bb;
                    const size_t idx = ((size_t)(b * 16 + h) * 2048 + s) * 64 + d;
                    outB[idx] = (f16_t)(v * scaleB);
                    outF[idx] = v;
                }
            } else {
                const int h = n >> 6, d = n & 63;
                const int m = m0 + crow0 + mi * 16;
                const int b = m >> 11, s = m & 2047;
                unsigned short us[4];
#pragma unroll
                for (int r = 0; r < 4; ++r) {
                    f16_t t = (f16_t)(acc[mi][ni][r] + bb);
                    us[r] = __builtin_bit_cast(unsigned short, t);
                }
                uint2 pk;
                pk.x = us[0] | ((unsigned)us[1] << 16);
                pk.y = us[2] | ((unsigned)us[3] << 16);
                *(uint2*)(outB + ((size_t)(b * 16 + h) * 64 + d) * 2048 + s) = pk;
            }
        }
    }
}

// ---------------------------------------------------------------------------
// Z-sweep (r12 + XCD swizzle): K-stationary, one barrier total.  Grid (512),
// 512 thr.  Bijective relabel puts all 16 tc-blocks of one bh on ONE XCD
// (4 bh/XCD -> Q+K working set 2 MB < 4 MB L2): xcd=id&7, j=id>>3,
// bh=xcd*4+(j&3), tc=j>>2.  partials[bh][s][tc16] = (sum exp2, max).
// ---------------------------------------------------------------------------
__global__ __launch_bounds__(512)
void attn_zsweep_kernel(const f16_t* __restrict__ qh, const f16_t* __restrict__ kh,
                        float2* __restrict__ partials)
{
    __shared__ __align__(16) char Klds[16384];   // [128 t][64 d] f16 swizzled

    const int tid = threadIdx.x;
    const int lane = tid & 63;
    const int g = lane >> 4;
    const int w = tid >> 6;
    const int id = blockIdx.x;
    const int bh = (id & 7) * 4 + ((id >> 3) & 3);
    const int tc = id >> 5;

    {
        const size_t kbase = ((size_t)bh * 2048 + tc * 128) * 64;
#pragma unroll
        for (int inst = 0; inst < 2; ++inst) {
            int L = inst * 8192 + tid * 16;
            int row = L >> 7;
            int k16 = ((L >> 4) & 7) ^ (row & 7);
            gload16(kh + kbase + (size_t)row * 64 + k16 * 8,
                    Klds + inst * 8192 + w * 1024);
        }
    }
    __syncthreads();   // only barrier in the kernel

    auto qload = [&](int si, f16x8& a, f16x8& b) {
        const size_t rb = ((size_t)bh * 2048 + si * 128 + w * 16 + (lane & 15)) * 64;
        a = *(const f16x8*)(qh + rb + g * 8);
        b = *(const f16x8*)(qh + rb + 32 + g * 8);
    };

    auto compute = [&](int si, f16x8 q0, f16x8 q1) {
        f32x4 acc[8] = {};
#pragma unroll
        for (int kf = 0; kf < 2; ++kf) {
            const f16x8 qf = kf ? q1 : q0;
            const int k16 = kf * 4 + g;
#pragma unroll
            for (int tg = 0; tg < 8; ++tg) {
                const int t = tg * 16 + (lane & 15);
                f16x8 bfr = *(const f16x8*)(Klds + (t << 7) + ((k16 ^ (t & 7)) << 4));
                acc[tg] = mfma16(qf, bfr, acc[tg]);
            }
        }
#pragma unroll
        for (int r = 0; r < 4; ++r) {
            float sm = 0.0f, mx = -1e30f;
#pragma unroll
            for (int tg = 0; tg < 8; ++tg) {
                const float l2 = acc[tg][r];
                sm += EXP2F(l2);
                mx = fmaxf(mx, l2);
            }
#pragma unroll
            for (int mk = 1; mk < 16; mk <<= 1) {
                sm += __shfl_xor(sm, mk);
                mx = fmaxf(mx, __shfl_xor(mx, mk));
            }
            if ((lane & 15) == 0) {
                const int srow = si * 128 + w * 16 + g * 4 + r;
                partials[((size_t)bh * 2048 + srow) * 16 + tc] = make_float2(sm, mx);
            }
        }
    };

    f16x8 qA0, qA1, qB0, qB1;
    qload(0, qA0, qA1);
    for (int si = 0; si < 16; si += 2) {
        qload(si + 1, qB0, qB1);
        compute(si, qA0, qA1);
        if (si + 2 < 16) qload(si + 2, qA0, qA1);
        compute(si + 1, qB0, qB1);
    }
}

// ---------------------------------------------------------------------------
// Z-reduce (r12): partials(16) -> lgZ + per-(bh, 64-row stile) dirty mask.
// ---------------------------------------------------------------------------
__global__ __launch_bounds__(256)
void zred_kernel(const float2* __restrict__ partials, float* __restrict__ stats,
                 unsigned* __restrict__ dirtymask)
{
    const int tid = threadIdx.x;
    const int bh = blockIdx.y;
    const int s = blockIdx.x * 256 + tid;
    const float4* p = (const float4*)(partials + ((size_t)bh * 2048 + s) * 16);
    float sm = 0.0f, mx = -1e30f;
#pragma unroll
    for (int i = 0; i < 8; ++i) {
        const float4 v = p[i];
        sm += v.x + v.z;
        mx = fmaxf(mx, fmaxf(v.y, v.w));
    }
    const float lgZ = LOG2F(sm);
    stats[(size_t)bh * 2048 + s] = lgZ;
    const bool dirty = mx > lgZ + LOG2_0P1 - 0.10f;
    const unsigned long long m = __ballot(dirty);
    if ((tid & 63) == 0)
        dirtymask[bh * 32 + (s >> 6)] = (m != 0ull) ? 1u : 0u;
}

// ---------------------------------------------------------------------------
// PV (r12): clean -> zero-fill merged slice; dirty (rare) -> chunk-flagged
// re-sweep with exact p + fp32 boundary arbitration + PV MFMA.
// ---------------------------------------------------------------------------
__global__ __launch_bounds__(256)
void attn_pv_kernel(const f16_t* __restrict__ qh, const f16_t* __restrict__ kh,
                    const f16_t* __restrict__ vT,
                    const float* __restrict__ qf32, const float* __restrict__ kf32,
                    const float* __restrict__ stats, const unsigned* __restrict__ dirtymask,
                    const float2* __restrict__ partials,
                    f16_t* __restrict__ merged)
{
    __shared__ __align__(16) char Klds[8192];
    __shared__ __align__(16) char Vlds[8192];
    __shared__ __align__(16) char Pl[4][2048];
    __shared__ unsigned cflags;

    const int tid = threadIdx.x;
    const int lane = tid & 63;
    const int g = lane >> 4;
    const int w = tid >> 6;
    const int s0 = blockIdx.x * 64;
    const int bh = blockIdx.y;
    const int b = bh >> 4, h = bh & 15;

    if (dirtymask[bh * 32 + blockIdx.x] == 0u) {
        const int row = s0 + (tid >> 2);
        f16_t* dst = merged + ((size_t)b * 2048 + row) * 1024 + h * 64 + (tid & 3) * 16;
        const uint4 z = {0u, 0u, 0u, 0u};
        *(uint4*)dst = z;
        *(uint4*)(dst + 8) = z;
        return;
    }

    // ---- rare dirty path ----
    f16x8 qf[2];
    float lgZ[4], lthr[4];
    {
        const size_t rowbase = ((size_t)bh * 2048 + s0 + w * 16 + (lane & 15)) * 64;
        qf[0] = *(const f16x8*)(qh + rowbase + g * 8);
        qf[1] = *(const f16x8*)(qh + rowbase + 32 + g * 8);
#pragma unroll
        for (int r = 0; r < 4; ++r) {
            lgZ[r] = stats[(size_t)bh * 2048 + s0 + w * 16 + g * 4 + r];
            lthr[r] = lgZ[r] + LOG2_0P1;
        }
    }

    // chunk-survivor flags from partials (per-row 128-t chunk maxima)
    if (tid == 0) cflags = 0u;
    __syncthreads();
    {
        unsigned f = 0;
#pragma unroll
        for (int r = 0; r < 4; ++r) {
            const size_t rowg = (size_t)bh * 2048 + s0 + w * 16 + g * 4 + r;
            const float thr = lthr[r] - 0.10f;
#pragma unroll
            for (int tc = 0; tc < 16; ++tc)
                if (partials[rowg * 16 + tc].y > thr) f |= (1u << tc);
        }
        if (f) atomicOr(&cflags, f);
    }
    __syncthreads();
    const unsigned flags = cflags;

    const size_t kbase = (size_t)bh * 2048 * 64;
    const size_t vbase = (size_t)bh * 64 * 2048;

    f32x4 hacc[4] = {};
    for (int tcc = 0; tcc < 2048; tcc += 64) {
        if (!((flags >> (tcc >> 7)) & 1u)) continue;   // block-uniform skip
#pragma unroll
        for (int inst = 0; inst < 2; ++inst) {
            int L = inst * 4096 + tid * 16;
            int t = L >> 7;
            int k16 = ((L >> 4) & 7) ^ (t & 7);
            gload16(kh + kbase + (size_t)(tcc + t) * 64 + k16 * 8,
                    Klds + inst * 4096 + w * 1024);
            int d = t;
            gload16(vT + vbase + (size_t)d * 2048 + tcc + k16 * 8,
                    Vlds + inst * 4096 + w * 1024);
        }
        __syncthreads();

        f32x4 acc[4] = {};
#pragma unroll
        for (int kf = 0; kf < 2; ++kf) {
            const int k16 = kf * 4 + g;
            f16x8 bfr[4];
#pragma unroll
            for (int tg = 0; tg < 4; ++tg) {
                int t = tg * 16 + (lane & 15);
                bfr[tg] = *(const f16x8*)(Klds + (t << 7) + ((k16 ^ (t & 7)) << 4));
            }
#pragma unroll
            for (int tg = 0; tg < 4; ++tg)
                acc[tg] = mfma16(qf[kf], bfr[tg], acc[tg]);
        }

        char* pb = Pl[w];
        bool any = false;
#pragma unroll
        for (int tg = 0; tg < 4; ++tg)
#pragma unroll
            for (int r = 0; r < 4; ++r) {
                const float l2 = acc[tg][r];
                float p = 0.0f;
                if (l2 > lthr[r] - 0.07f) {
                    if (fabsf(l2 - lthr[r]) < 0.07f) {
                        const float* qr = qf32 + ((size_t)bh * 2048 + s0 + w * 16 + g * 4 + r) * 64;
                        const float* kr = kf32 + ((size_t)bh * 2048 + tcc + tg * 16 + (lane & 15)) * 64;
                        float dt = 0.0f;
                        for (int dd = 0; dd < 64; ++dd) dt += qr[dd] * kr[dd];
                        const float pe = EXP2F(dt * SCL2 - lgZ[r]);
                        p = (pe > 0.1f) ? pe : 0.0f;
                    } else {
                        p = EXP2F(l2 - lgZ[r]);
                    }
                }
                any |= (p != 0.0f);
                const int row = g * 4 + r;
                const int t = tg * 16 + (lane & 15);
                *(f16_t*)(pb + (row << 7) + ((2 * t) ^ ((row & 7) << 4))) = (f16_t)p;
            }

        if (__ballot(any) != 0ull) {
#pragma unroll
            for (int kf = 0; kf < 2; ++kf) {
                const int t16 = kf * 4 + g;
                f16x8 pa, vb[4];
                {
                    const int row = lane & 15;
                    pa = *(const f16x8*)(pb + (row << 7) + ((t16 ^ (row & 7)) << 4));
                }
#pragma unroll
                for (int ni = 0; ni < 4; ++ni) {
                    const int d = ni * 16 + (lane & 15);
                    vb[ni] = *(const f16x8*)(Vlds + (d << 7) + ((t16 ^ (d & 7)) << 4));
                }
#pragma unroll
                for (int ni = 0; ni < 4; ++ni)
                    hacc[ni] = mfma16(pa, vb[ni], hacc[ni]);
            }
        }
        __syncthreads();
    }

#pragma unroll
    for (int ni = 0; ni < 4; ++ni)
#pragma unroll
        for (int r = 0; r < 4; ++r) {
            const int srow = s0 + w * 16 + g * 4 + r;
            const int col = h * 64 + ni * 16 + (lane & 15);
            merged[((size_t)b * 2048 + srow) * 1024 + col] = (f16_t)hacc[ni][r];
        }
}

// ---------------------------------------------------------------------------
// Adjacency (r12 + XCD swizzle): grid (1024), 256 thr, 2-buf __syncthreads
// K schedule + Q register ping-pong, LB(256,4).  Bijective relabel
// co-locates same-(b,tc) blocks (shared 256 KB K panel) on one XCD:
// xcd=id&7, j=id>>3, btc=xcd*4+(j&3), sc=j>>2; tc=btc&15... 32 (b,tc) combos
// -> 4/XCD, K working set 1 MB.
// ---------------------------------------------------------------------------
__global__ __launch_bounds__(256, 4)
void attn_adj_kernel(const f16_t* __restrict__ qh, const f16_t* __restrict__ kh,
                     const float* __restrict__ stats, float* __restrict__ adj)
{
    __shared__ __align__(16) char Klds[2][16384];  // [128 t][64 d] f16 swizzled
    __shared__ __align__(16) float Sl[16 * 64];    // [16 h][64 s] lgZ

    const int tid = threadIdx.x;
    const int lane = tid & 63;
    const int g = lane >> 4;
    const int w = tid >> 6;
    const int id = blockIdx.x;
    const int btc = (id & 7) * 4 + ((id >> 3) & 3);   // 0..31
    const int sc  = id >> 5;                          // 0..31
    const int t0 = (btc & 15) * 128;
    const int s0 = sc * 64;
    const int b  = btc >> 4;

    // stage all 16 heads' stats via plain loads (covered by first barrier)
    {
        const int hh = tid >> 4;
        const int sl = (tid * 4) & 63;
        const float4 v = *(const float4*)(stats + ((size_t)(b * 16 + hh) * 2048 + s0 + sl));
        *(float4*)&Sl[tid * 4] = v;
    }

    auto stageK = [&](int h, int buf) {
        const size_t kbase = ((size_t)(b * 16 + h) * 2048 + t0) * 64;
#pragma unroll
        for (int inst = 0; inst < 4; ++inst) {
            int L = inst * 4096 + tid * 16;
            int row = L >> 7;
            int k16 = ((L >> 4) & 7) ^ (row & 7);
            gload16(kh + kbase + (size_t)row * 64 + k16 * 8,
                    Klds[buf] + inst * 4096 + w * 1024);
        }
    };
    auto qload = [&](int h, f16x8& a, f16x8& bq) {
        const size_t rb = ((size_t)(b * 16 + h) * 2048 + s0 + w * 16 + (lane & 15)) * 64;
        a  = *(const f16x8*)(qh + rb + g * 8);
        bq = *(const f16x8*)(qh + rb + 32 + g * 8);
    };

    f32x4 aacc[8] = {};

    auto body = [&](int h, f16x8 q0, f16x8 q1) {
        float cc[4];
#pragma unroll
        for (int r = 0; r < 4; ++r)
            cc[r] = Sl[h * 64 + w * 16 + g * 4 + r] + 4.0f;   // +4: fold mean_h
        const char* Kb = Klds[h & 1];
        f32x4 acc[8] = {};
#pragma unroll
        for (int kf = 0; kf < 2; ++kf) {
            const f16x8 qf = kf ? q1 : q0;
            const int k16 = kf * 4 + g;
#pragma unroll
            for (int tg = 0; tg < 8; ++tg) {
                const int t = tg * 16 + (lane & 15);
                const f16x8 bfr = *(const f16x8*)(Kb + (t << 7) + ((k16 ^ (t & 7)) << 4));
                acc[tg] = mfma16(qf, bfr, acc[tg]);
            }
        }
#pragma unroll
        for (int tg = 0; tg < 8; ++tg)
#pragma unroll
            for (int r = 0; r < 4; ++r)
                aacc[tg][r] += EXP2F(acc[tg][r] - cc[r]);
    };

    f16x8 qA0, qA1, qB0, qB1;
    stageK(0, 0);
    qload(0, qA0, qA1);
    __syncthreads();   // buf0 + stats ready (drains q0 loads too)

    for (int h = 0; h < 16; h += 2) {
        if (h + 1 < 16) { stageK(h + 1, (h + 1) & 1); qload(h + 1, qB0, qB1); }
        body(h, qA0, qA1);
        __syncthreads();
        if (h + 2 < 16) { stageK(h + 2, (h + 2) & 1); qload(h + 2, qA0, qA1); }
        body(h + 1, qB0, qB1);
        __syncthreads();
    }

#pragma unroll
    for (int tg = 0; tg < 8; ++tg)
#pragma unroll
        for (int r = 0; r < 4; ++r) {
            const int s = s0 + w * 16 + g * 4 + r;
            adj[((size_t)b * 2048 + s) * 2048 + t0 + tg * 16 + (lane & 15)] = aacc[tg][r];
        }
}

// ---------------------------------------------------------------------------
extern "C" void kernel_launch(void* const* d_in, const int* in_sizes, int n_in,
                              void* d_out, int out_size, void* d_ws, size_t ws_size,
                              hipStream_t stream)
{
    (void)in_sizes; (void)n_in; (void)out_size; (void)ws_size;

    const float* queries = (const float*)d_in[0];
    const float* keys    = (const float*)d_in[1];
    const float* values  = (const float*)d_in[2];
    const float* Wq = (const float*)d_in[3];
    const float* bq = (const float*)d_in[4];
    const float* Wk = (const float*)d_in[5];
    const float* bk = (const float*)d_in[6];
    const float* Wv = (const float*)d_in[7];
    const float* bv = (const float*)d_in[8];
    const float* Wp = (const float*)d_in[9];
    const float* bp = (const float*)d_in[10];

    float* out = (float*)d_out;
    float* adj = out + OUT_ELEMS;

    // workspace layout (bytes).  partials/dirtymask overlay Xq/Xv (dead
    // after the projection GEMMs).
    char* ws = (char*)d_ws;
    f16_t* Xq   = (f16_t*)(ws);                    // [4096][1024] f16   8.39 MB
    f16_t* Xk   = (f16_t*)(ws + 8388608);
    f16_t* Xv   = (f16_t*)(ws + 16777216);
    f16_t* Wqh  = (f16_t*)(ws + 25165824);         // [1024][1024] f16
    f16_t* Wkh  = (f16_t*)(ws + 27262976);
    f16_t* Wvh  = (f16_t*)(ws + 29360128);
    f16_t* Wph  = (f16_t*)(ws + 31457280);
    f16_t* qh16 = (f16_t*)(ws + 33554432);         // [32][2048][64] f16
    f16_t* kh16 = (f16_t*)(ws + 41943040);
    f16_t* vT   = (f16_t*)(ws + 50331648);         // [32][64][2048] f16
    f16_t* mg   = (f16_t*)(ws + 58720256);         // [4096][1024] f16
    float* qf32 = (float*)(ws + 67108864);         // [32][2048][64] f32
    float* kf32 = (float*)(ws + 83886080);
    float* stats = (float*)(ws + 100663296);       // [32][2048] lgZ
    float2* partials  = (float2*)(ws);             // [32][2048][16] f2 = 8.4 MB (overlays Xq)
    unsigned* dirtymask = (unsigned*)(ws + 16777216 + 4194304);  // inside dead Xv

    prep_kernel<<<dim3(4096, 7), 256, 0, stream>>>(
        (const float4*)queries, (const float4*)keys, (const float4*)values,
        (const float4*)Wq, (const float4*)Wk, (const float4*)Wv, (const float4*)Wp,
        (unsigned short*)Xq, (unsigned short*)Xk, (unsigned short*)Xv,
        (unsigned short*)Wqh, (unsigned short*)Wkh, (unsigned short*)Wvh,
        (unsigned short*)Wph);

    const dim3 gg(8, 32);
    gemm_mfma<0><<<gg, 512, 0, stream>>>(Xq, Wqh, bq, SCL2, qf32, qh16, nullptr);
    gemm_mfma<0><<<gg, 512, 0, stream>>>(Xk, Wkh, bk, 1.0f, kf32, kh16, nullptr);
    gemm_mfma<1><<<gg, 512, 0, stream>>>(Xv, Wvh, bv, 1.0f, nullptr, vT, nullptr);

    attn_zsweep_kernel<<<dim3(512), 512, 0, stream>>>(qh16, kh16, partials);
    zred_kernel<<<dim3(8, 32), 256, 0, stream>>>(partials, stats, dirtymask);
    attn_pv_kernel<<<dim3(32, 32), 256, 0, stream>>>(qh16, kh16, vT, qf32, kf32,
                                                     stats, dirtymask, partials, mg);
    attn_adj_kernel<<<dim3(1024), 256, 0, stream>>>(qh16, kh16, stats, adj);

    gemm_mfma<2><<<gg, 512, 0, stream>>>(mg, Wph, bp, 1.0f, out, nullptr, dirtymask);
}

// Round 17
// 166.188 us; speedup vs baseline: 1.0756x; 1.0572x over previous
//
#include <hip/hip_runtime.h>
#include <cstddef>
#include <cstdint>

// Problem constants: B=2, S=2048, E=1024, H=16, DK=64
constexpr size_t OUT_ELEMS = (size_t)2 * 2048 * 1024;   // 4,194,304

typedef _Float16 f16_t;
typedef __attribute__((ext_vector_type(8))) _Float16 f16x8;
typedef __attribute__((ext_vector_type(4))) float f32x4;

#define SCL2      0.1803368801111204f    // 0.125 * log2(e): logits in log2 domain
#define LOG2_0P1  -3.3219280948873623f   // log2(0.1)

#define EXP2F(x)  __builtin_amdgcn_exp2f(x)
#define LOG2F(x)  __builtin_amdgcn_logf(x)

#define WAITV(N)  asm volatile("s_waitcnt vmcnt(" #N ")" ::: "memory")
__device__ __forceinline__ void ringbar() {
    __builtin_amdgcn_s_barrier();
    __builtin_amdgcn_sched_barrier(0);
}

__device__ __forceinline__ f32x4 mfma16(f16x8 a, f16x8 b, f32x4 c) {
    return __builtin_amdgcn_mfma_f32_16x16x32_f16(a, b, c, 0, 0, 0);
}

__device__ __forceinline__ void gload16(const void* g, void* l) {
    __builtin_amdgcn_global_load_lds(
        (const __attribute__((address_space(1))) void*)g,
        (__attribute__((address_space(3))) void*)l, 16, 0, 0);
}

// ---------------------------------------------------------------------------
// Input prep: all 7 tensors -> plain f16.  grid (4096, 7).
// ---------------------------------------------------------------------------
__global__ __launch_bounds__(256)
void prep_kernel(const float4* __restrict__ q, const float4* __restrict__ k,
                 const float4* __restrict__ v, const float4* __restrict__ wq,
                 const float4* __restrict__ wk, const float4* __restrict__ wv,
                 const float4* __restrict__ wp,
                 unsigned short* __restrict__ xq, unsigned short* __restrict__ xk,
                 unsigned short* __restrict__ xv, unsigned short* __restrict__ wqh,
                 unsigned short* __restrict__ wkh, unsigned short* __restrict__ wvh,
                 unsigned short* __restrict__ wph)
{
    const int z = blockIdx.y;
    const int i = blockIdx.x * 256 + threadIdx.x;
    const float4* src; unsigned short* dst; int total4;
    switch (z) {
        case 0:  src = q;  dst = xq;  total4 = 1048576; break;
        case 1:  src = k;  dst = xk;  total4 = 1048576; break;
        case 2:  src = v;  dst = xv;  total4 = 1048576; break;
        case 3:  src = wq; dst = wqh; total4 = 262144;  break;
        case 4:  src = wk; dst = wkh; total4 = 262144;  break;
        case 5:  src = wv; dst = wvh; total4 = 262144;  break;
        default: src = wp; dst = wph; total4 = 262144;  break;
    }
    if (i >= total4) return;
    const float4 v4 = src[i];
    const float vv[4] = {v4.x, v4.y, v4.z, v4.w};
    unsigned short u[4];
#pragma unroll
    for (int j = 0; j < 4; ++j) {
        f16_t h = (f16_t)vv[j];
        u[j] = __builtin_bit_cast(unsigned short, h);
    }
    uint2 w;
    w.x = u[0] | ((unsigned)u[1] << 16); w.y = u[2] | ((unsigned)u[3] << 16);
    *(uint2*)(dst + (size_t)i * 4) = w;
}

// ---------------------------------------------------------------------------
// MFMA GEMM (r12, proven): 128x128 tile, BK=64, 512 thr, NB=3 ring, counted
// vmcnt(4) (pure-gload16 FIFO -> counted waits sound).
// OUTMODE: 0 = Q/K f16 [bh][s][64] (x scaleB) + raw f32; 1 = vT f16; 2 = f32.
// OUTMODE 2: clean M-tiles (no dirty merged rows) write out = bias and exit.
// ---------------------------------------------------------------------------
template<int OUTMODE>
__global__ __launch_bounds__(512)
void gemm_mfma(const f16_t* __restrict__ A, const f16_t* __restrict__ B,
               const float* __restrict__ bias, float scaleB,
               float* __restrict__ outF, f16_t* __restrict__ outB,
               const unsigned* __restrict__ dmask)
{
    __shared__ __align__(16) char Asl[3][16384];
    __shared__ __align__(16) char Bsl[3][16384];

    const int tid = threadIdx.x;
    const int lane = tid & 63;
    const int w = tid >> 6;
    const int wm = w >> 1;
    const int wn = w & 1;
    const int n0 = blockIdx.x * 128;
    const int m0 = blockIdx.y * 128;

    if (OUTMODE == 2) {
        const int bb = m0 >> 11;
        const int st0 = (m0 & 2047) >> 6;
        unsigned dd = 0;
        for (int hh = 0; hh < 16; ++hh)
            dd |= dmask[(bb * 16 + hh) * 32 + st0] | dmask[(bb * 16 + hh) * 32 + st0 + 1];
        if (dd == 0u) {
            const int row = tid >> 2;
            const int c0 = (tid & 3) * 32;
            float* dst = outF + (size_t)(m0 + row) * 1024 + n0 + c0;
#pragma unroll
            for (int j = 0; j < 8; ++j)
                *(float4*)(dst + j * 4) = *(const float4*)(bias + n0 + c0 + j * 4);
            return;
        }
    }

    f32x4 acc[2][4] = {};

    auto stage = [&](int ki, int buf) {
        const int kt = ki * 64;
#pragma unroll
        for (int inst = 0; inst < 2; ++inst) {
            int L = inst * 8192 + tid * 16;
            int row = L >> 7;
            int k16 = ((L >> 4) & 7) ^ (row & 7);
            gload16(A + (size_t)(m0 + row) * 1024 + kt + k16 * 8,
                    Asl[buf] + inst * 8192 + w * 1024);
            gload16(B + (size_t)(n0 + row) * 1024 + kt + k16 * 8,
                    Bsl[buf] + inst * 8192 + w * 1024);
        }
    };

    stage(0, 0);

    for (int ki = 0; ki < 16; ++ki) {
        if (ki + 1 < 16) stage(ki + 1, (ki + 1) % 3);
        if (ki < 15) { WAITV(4); } else { WAITV(0); }
        ringbar();
        const char* Ab = Asl[ki % 3];
        const char* Bb = Bsl[ki % 3];
#pragma unroll
        for (int kf = 0; kf < 2; ++kf) {
            const int k16 = kf * 4 + (lane >> 4);
            f16x8 af[2], bfr[4];
#pragma unroll
            for (int mi = 0; mi < 2; ++mi) {
                int row = wm * 32 + mi * 16 + (lane & 15);
                af[mi] = *(const f16x8*)(Ab + (row << 7) + ((k16 ^ (row & 7)) << 4));
            }
#pragma unroll
            for (int ni = 0; ni < 4; ++ni) {
                int row = wn * 64 + ni * 16 + (lane & 15);
                bfr[ni] = *(const f16x8*)(Bb + (row << 7) + ((k16 ^ (row & 7)) << 4));
            }
#pragma unroll
            for (int mi = 0; mi < 2; ++mi)
#pragma unroll
                for (int ni = 0; ni < 4; ++ni)
                    acc[mi][ni] = mfma16(af[mi], bfr[ni], acc[mi][ni]);
        }
    }

    const int crow0 = wm * 32 + (lane >> 4) * 4;
    const int ccol0 = wn * 64 + (lane & 15);
#pragma unroll
    for (int mi = 0; mi < 2; ++mi) {
#pragma unroll
        for (int ni = 0; ni < 4; ++ni) {
            const int n = n0 + ccol0 + ni * 16;
            const float bb = bias[n];
            if (OUTMODE == 2) {
#pragma unroll
                for (int r = 0; r < 4; ++r) {
                    const int m = m0 + crow0 + mi * 16 + r;
                    outF[(size_t)m * 1024 + n] = acc[mi][ni][r] + bb;
                }
            } else if (OUTMODE == 0) {
                const int h = n >> 6, d = n & 63;
#pragma unroll
                for (int r = 0; r < 4; ++r) {
                    const int m = m0 + crow0 + mi * 16 + r;
                    const int b = m >> 11, s = m & 2047;
                    const float v = acc[mi][ni][r] + bb;
                    const size_t idx = ((size_t)(b * 16 + h) * 2048 + s) * 64 + d;
                    outB[idx] = (f16_t)(v * scaleB);
                    outF[idx] = v;
                }
            } else {
                const int h = n >> 6, d = n & 63;
                const int m = m0 + crow0 + mi * 16;
                const int b = m >> 11, s = m & 2047;
                unsigned short us[4];
#pragma unroll
                for (int r = 0; r < 4; ++r) {
                    f16_t t = (f16_t)(acc[mi][ni][r] + bb);
                    us[r] = __builtin_bit_cast(unsigned short, t);
                }
                uint2 pk;
                pk.x = us[0] | ((unsigned)us[1] << 16);
                pk.y = us[2] | ((unsigned)us[3] << 16);
                *(uint2*)(outB + ((size_t)(b * 16 + h) * 64 + d) * 2048 + s) = pk;
            }
        }
    }
}

// ---------------------------------------------------------------------------
// Z-sweep (r12 exact, proven 41.6 us): K-stationary, one barrier total.
// Grid (16 tc, 32 bh), 512 thr.  partials[bh][s][tc16] = (sum exp2, max).
// (r16's XCD swizzle cut FETCH 4.5x but ADDED 10 us -> latency-bound, reverted.)
// ---------------------------------------------------------------------------
__global__ __launch_bounds__(512)
void attn_zsweep_kernel(const f16_t* __restrict__ qh, const f16_t* __restrict__ kh,
                        float2* __restrict__ partials)
{
    __shared__ __align__(16) char Klds[16384];   // [128 t][64 d] f16 swizzled

    const int tid = threadIdx.x;
    const int lane = tid & 63;
    const int g = lane >> 4;
    const int w = tid >> 6;
    const int tc = blockIdx.x;
    const int bh = blockIdx.y;

    {
        const size_t kbase = ((size_t)bh * 2048 + tc * 128) * 64;
#pragma unroll
        for (int inst = 0; inst < 2; ++inst) {
            int L = inst * 8192 + tid * 16;
            int row = L >> 7;
            int k16 = ((L >> 4) & 7) ^ (row & 7);
            gload16(kh + kbase + (size_t)row * 64 + k16 * 8,
                    Klds + inst * 8192 + w * 1024);
        }
    }
    __syncthreads();   // only barrier in the kernel

    auto qload = [&](int si, f16x8& a, f16x8& b) {
        const size_t rb = ((size_t)bh * 2048 + si * 128 + w * 16 + (lane & 15)) * 64;
        a = *(const f16x8*)(qh + rb + g * 8);
        b = *(const f16x8*)(qh + rb + 32 + g * 8);
    };

    auto compute = [&](int si, f16x8 q0, f16x8 q1) {
        f32x4 acc[8] = {};
#pragma unroll
        for (int kf = 0; kf < 2; ++kf) {
            const f16x8 qf = kf ? q1 : q0;
            const int k16 = kf * 4 + g;
#pragma unroll
            for (int tg = 0; tg < 8; ++tg) {
                const int t = tg * 16 + (lane & 15);
                f16x8 bfr = *(const f16x8*)(Klds + (t << 7) + ((k16 ^ (t & 7)) << 4));
                acc[tg] = mfma16(qf, bfr, acc[tg]);
            }
        }
#pragma unroll
        for (int r = 0; r < 4; ++r) {
            float sm = 0.0f, mx = -1e30f;
#pragma unroll
            for (int tg = 0; tg < 8; ++tg) {
                const float l2 = acc[tg][r];
                sm += EXP2F(l2);
                mx = fmaxf(mx, l2);
            }
#pragma unroll
            for (int mk = 1; mk < 16; mk <<= 1) {
                sm += __shfl_xor(sm, mk);
                mx = fmaxf(mx, __shfl_xor(mx, mk));
            }
            if ((lane & 15) == 0) {
                const int srow = si * 128 + w * 16 + g * 4 + r;
                partials[((size_t)bh * 2048 + srow) * 16 + tc] = make_float2(sm, mx);
            }
        }
    };

    f16x8 qA0, qA1, qB0, qB1;
    qload(0, qA0, qA1);
    for (int si = 0; si < 16; si += 2) {
        qload(si + 1, qB0, qB1);
        compute(si, qA0, qA1);
        if (si + 2 < 16) qload(si + 2, qA0, qA1);
        compute(si + 1, qB0, qB1);
    }
}

// ---------------------------------------------------------------------------
// Z-reduce (r12): partials(16) -> lgZ + per-(bh, 64-row stile) dirty mask.
// ---------------------------------------------------------------------------
__global__ __launch_bounds__(256)
void zred_kernel(const float2* __restrict__ partials, float* __restrict__ stats,
                 unsigned* __restrict__ dirtymask)
{
    const int tid = threadIdx.x;
    const int bh = blockIdx.y;
    const int s = blockIdx.x * 256 + tid;
    const float4* p = (const float4*)(partials + ((size_t)bh * 2048 + s) * 16);
    float sm = 0.0f, mx = -1e30f;
#pragma unroll
    for (int i = 0; i < 8; ++i) {
        const float4 v = p[i];
        sm += v.x + v.z;
        mx = fmaxf(mx, fmaxf(v.y, v.w));
    }
    const float lgZ = LOG2F(sm);
    stats[(size_t)bh * 2048 + s] = lgZ;
    const bool dirty = mx > lgZ + LOG2_0P1 - 0.10f;
    const unsigned long long m = __ballot(dirty);
    if ((tid & 63) == 0)
        dirtymask[bh * 32 + (s >> 6)] = (m != 0ull) ? 1u : 0u;
}

// ---------------------------------------------------------------------------
// PV (r12): clean -> zero-fill merged slice; dirty (rare) -> chunk-flagged
// re-sweep with exact p + fp32 boundary arbitration + PV MFMA.
// ---------------------------------------------------------------------------
__global__ __launch_bounds__(256)
void attn_pv_kernel(const f16_t* __restrict__ qh, const f16_t* __restrict__ kh,
                    const f16_t* __restrict__ vT,
                    const float* __restrict__ qf32, const float* __restrict__ kf32,
                    const float* __restrict__ stats, const unsigned* __restrict__ dirtymask,
                    const float2* __restrict__ partials,
                    f16_t* __restrict__ merged)
{
    __shared__ __align__(16) char Klds[8192];
    __shared__ __align__(16) char Vlds[8192];
    __shared__ __align__(16) char Pl[4][2048];
    __shared__ unsigned cflags;

    const int tid = threadIdx.x;
    const int lane = tid & 63;
    const int g = lane >> 4;
    const int w = tid >> 6;
    const int s0 = blockIdx.x * 64;
    const int bh = blockIdx.y;
    const int b = bh >> 4, h = bh & 15;

    if (dirtymask[bh * 32 + blockIdx.x] == 0u) {
        const int row = s0 + (tid >> 2);
        f16_t* dst = merged + ((size_t)b * 2048 + row) * 1024 + h * 64 + (tid & 3) * 16;
        const uint4 z = {0u, 0u, 0u, 0u};
        *(uint4*)dst = z;
        *(uint4*)(dst + 8) = z;
        return;
    }

    // ---- rare dirty path ----
    f16x8 qf[2];
    float lgZ[4], lthr[4];
    {
        const size_t rowbase = ((size_t)bh * 2048 + s0 + w * 16 + (lane & 15)) * 64;
        qf[0] = *(const f16x8*)(qh + rowbase + g * 8);
        qf[1] = *(const f16x8*)(qh + rowbase + 32 + g * 8);
#pragma unroll
        for (int r = 0; r < 4; ++r) {
            lgZ[r] = stats[(size_t)bh * 2048 + s0 + w * 16 + g * 4 + r];
            lthr[r] = lgZ[r] + LOG2_0P1;
        }
    }

    // chunk-survivor flags from partials (per-row 128-t chunk maxima)
    if (tid == 0) cflags = 0u;
    __syncthreads();
    {
        unsigned f = 0;
#pragma unroll
        for (int r = 0; r < 4; ++r) {
            const size_t rowg = (size_t)bh * 2048 + s0 + w * 16 + g * 4 + r;
            const float thr = lthr[r] - 0.10f;
#pragma unroll
            for (int tc = 0; tc < 16; ++tc)
                if (partials[rowg * 16 + tc].y > thr) f |= (1u << tc);
        }
        if (f) atomicOr(&cflags, f);
    }
    __syncthreads();
    const unsigned flags = cflags;

    const size_t kbase = (size_t)bh * 2048 * 64;
    const size_t vbase = (size_t)bh * 64 * 2048;

    f32x4 hacc[4] = {};
    for (int tcc = 0; tcc < 2048; tcc += 64) {
        if (!((flags >> (tcc >> 7)) & 1u)) continue;   // block-uniform skip
#pragma unroll
        for (int inst = 0; inst < 2; ++inst) {
            int L = inst * 4096 + tid * 16;
            int t = L >> 7;
            int k16 = ((L >> 4) & 7) ^ (t & 7);
            gload16(kh + kbase + (size_t)(tcc + t) * 64 + k16 * 8,
                    Klds + inst * 4096 + w * 1024);
            int d = t;
            gload16(vT + vbase + (size_t)d * 2048 + tcc + k16 * 8,
                    Vlds + inst * 4096 + w * 1024);
        }
        __syncthreads();

        f32x4 acc[4] = {};
#pragma unroll
        for (int kf = 0; kf < 2; ++kf) {
            const int k16 = kf * 4 + g;
            f16x8 bfr[4];
#pragma unroll
            for (int tg = 0; tg < 4; ++tg) {
                int t = tg * 16 + (lane & 15);
                bfr[tg] = *(const f16x8*)(Klds + (t << 7) + ((k16 ^ (t & 7)) << 4));
            }
#pragma unroll
            for (int tg = 0; tg < 4; ++tg)
                acc[tg] = mfma16(qf[kf], bfr[tg], acc[tg]);
        }

        char* pb = Pl[w];
        bool any = false;
#pragma unroll
        for (int tg = 0; tg < 4; ++tg)
#pragma unroll
            for (int r = 0; r < 4; ++r) {
                const float l2 = acc[tg][r];
                float p = 0.0f;
                if (l2 > lthr[r] - 0.07f) {
                    if (fabsf(l2 - lthr[r]) < 0.07f) {
                        const float* qr = qf32 + ((size_t)bh * 2048 + s0 + w * 16 + g * 4 + r) * 64;
                        const float* kr = kf32 + ((size_t)bh * 2048 + tcc + tg * 16 + (lane & 15)) * 64;
                        float dt = 0.0f;
                        for (int dd = 0; dd < 64; ++dd) dt += qr[dd] * kr[dd];
                        const float pe = EXP2F(dt * SCL2 - lgZ[r]);
                        p = (pe > 0.1f) ? pe : 0.0f;
                    } else {
                        p = EXP2F(l2 - lgZ[r]);
                    }
                }
                any |= (p != 0.0f);
                const int row = g * 4 + r;
                const int t = tg * 16 + (lane & 15);
                *(f16_t*)(pb + (row << 7) + ((2 * t) ^ ((row & 7) << 4))) = (f16_t)p;
            }

        if (__ballot(any) != 0ull) {
#pragma unroll
            for (int kf = 0; kf < 2; ++kf) {
                const int t16 = kf * 4 + g;
                f16x8 pa, vb[4];
                {
                    const int row = lane & 15;
                    pa = *(const f16x8*)(pb + (row << 7) + ((t16 ^ (row & 7)) << 4));
                }
#pragma unroll
                for (int ni = 0; ni < 4; ++ni) {
                    const int d = ni * 16 + (lane & 15);
                    vb[ni] = *(const f16x8*)(Vlds + (d << 7) + ((t16 ^ (d & 7)) << 4));
                }
#pragma unroll
                for (int ni = 0; ni < 4; ++ni)
                    hacc[ni] = mfma16(pa, vb[ni], hacc[ni]);
            }
        }
        __syncthreads();
    }

#pragma unroll
    for (int ni = 0; ni < 4; ++ni)
#pragma unroll
        for (int r = 0; r < 4; ++r) {
            const int srow = s0 + w * 16 + g * 4 + r;
            const int col = h * 64 + ni * 16 + (lane & 15);
            merged[((size_t)b * 2048 + srow) * 1024 + col] = (f16_t)hacc[ni][r];
        }
}

// ---------------------------------------------------------------------------
// Adjacency (r12 schedule + r16 XCD swizzle, kept: total accounting showed
// ~3.6 us gain from co-locating same-(b,tc) blocks -> shared 256 KB K panel
// per XCD).  Grid (1024), 256 thr, 2-buf __syncthreads K schedule + Q
// register ping-pong, LB(256,4).
// ---------------------------------------------------------------------------
__global__ __launch_bounds__(256, 4)
void attn_adj_kernel(const f16_t* __restrict__ qh, const f16_t* __restrict__ kh,
                     const float* __restrict__ stats, float* __restrict__ adj)
{
    __shared__ __align__(16) char Klds[2][16384];  // [128 t][64 d] f16 swizzled
    __shared__ __align__(16) float Sl[16 * 64];    // [16 h][64 s] lgZ

    const int tid = threadIdx.x;
    const int lane = tid & 63;
    const int g = lane >> 4;
    const int w = tid >> 6;
    const int id = blockIdx.x;
    const int btc = (id & 7) * 4 + ((id >> 3) & 3);   // 0..31
    const int sc  = id >> 5;                          // 0..31
    const int t0 = (btc & 15) * 128;
    const int s0 = sc * 64;
    const int b  = btc >> 4;

    // stage all 16 heads' stats via plain loads (covered by first barrier)
    {
        const int hh = tid >> 4;
        const int sl = (tid * 4) & 63;
        const float4 v = *(const float4*)(stats + ((size_t)(b * 16 + hh) * 2048 + s0 + sl));
        *(float4*)&Sl[tid * 4] = v;
    }

    auto stageK = [&](int h, int buf) {
        const size_t kbase = ((size_t)(b * 16 + h) * 2048 + t0) * 64;
#pragma unroll
        for (int inst = 0; inst < 4; ++inst) {
            int L = inst * 4096 + tid * 16;
            int row = L >> 7;
            int k16 = ((L >> 4) & 7) ^ (row & 7);
            gload16(kh + kbase + (size_t)row * 64 + k16 * 8,
                    Klds[buf] + inst * 4096 + w * 1024);
        }
    };
    auto qload = [&](int h, f16x8& a, f16x8& bq) {
        const size_t rb = ((size_t)(b * 16 + h) * 2048 + s0 + w * 16 + (lane & 15)) * 64;
        a  = *(const f16x8*)(qh + rb + g * 8);
        bq = *(const f16x8*)(qh + rb + 32 + g * 8);
    };

    f32x4 aacc[8] = {};

    auto body = [&](int h, f16x8 q0, f16x8 q1) {
        float cc[4];
#pragma unroll
        for (int r = 0; r < 4; ++r)
            cc[r] = Sl[h * 64 + w * 16 + g * 4 + r] + 4.0f;   // +4: fold mean_h
        const char* Kb = Klds[h & 1];
        f32x4 acc[8] = {};
#pragma unroll
        for (int kf = 0; kf < 2; ++kf) {
            const f16x8 qf = kf ? q1 : q0;
            const int k16 = kf * 4 + g;
#pragma unroll
            for (int tg = 0; tg < 8; ++tg) {
                const int t = tg * 16 + (lane & 15);
                const f16x8 bfr = *(const f16x8*)(Kb + (t << 7) + ((k16 ^ (t & 7)) << 4));
                acc[tg] = mfma16(qf, bfr, acc[tg]);
            }
        }
#pragma unroll
        for (int tg = 0; tg < 8; ++tg)
#pragma unroll
            for (int r = 0; r < 4; ++r)
                aacc[tg][r] += EXP2F(acc[tg][r] - cc[r]);
    };

    f16x8 qA0, qA1, qB0, qB1;
    stageK(0, 0);
    qload(0, qA0, qA1);
    __syncthreads();   // buf0 + stats ready (drains q0 loads too)

    for (int h = 0; h < 16; h += 2) {
        if (h + 1 < 16) { stageK(h + 1, (h + 1) & 1); qload(h + 1, qB0, qB1); }
        body(h, qA0, qA1);
        __syncthreads();
        if (h + 2 < 16) { stageK(h + 2, (h + 2) & 1); qload(h + 2, qA0, qA1); }
        body(h + 1, qB0, qB1);
        __syncthreads();
    }

#pragma unroll
    for (int tg = 0; tg < 8; ++tg)
#pragma unroll
        for (int r = 0; r < 4; ++r) {
            const int s = s0 + w * 16 + g * 4 + r;
            adj[((size_t)b * 2048 + s) * 2048 + t0 + tg * 16 + (lane & 15)] = aacc[tg][r];
        }
}

// ---------------------------------------------------------------------------
extern "C" void kernel_launch(void* const* d_in, const int* in_sizes, int n_in,
                              void* d_out, int out_size, void* d_ws, size_t ws_size,
                              hipStream_t stream)
{
    (void)in_sizes; (void)n_in; (void)out_size; (void)ws_size;

    const float* queries = (const float*)d_in[0];
    const float* keys    = (const float*)d_in[1];
    const float* values  = (const float*)d_in[2];
    const float* Wq = (const float*)d_in[3];
    const float* bq = (const float*)d_in[4];
    const float* Wk = (const float*)d_in[5];
    const float* bk = (const float*)d_in[6];
    const float* Wv = (const float*)d_in[7];
    const float* bv = (const float*)d_in[8];
    const float* Wp = (const float*)d_in[9];
    const float* bp = (const float*)d_in[10];

    float* out = (float*)d_out;
    float* adj = out + OUT_ELEMS;

    // workspace layout (bytes).  partials/dirtymask overlay Xq/Xv (dead
    // after the projection GEMMs).
    char* ws = (char*)d_ws;
    f16_t* Xq   = (f16_t*)(ws);                    // [4096][1024] f16   8.39 MB
    f16_t* Xk   = (f16_t*)(ws + 8388608);
    f16_t* Xv   = (f16_t*)(ws + 16777216);
    f16_t* Wqh  = (f16_t*)(ws + 25165824);         // [1024][1024] f16
    f16_t* Wkh  = (f16_t*)(ws + 27262976);
    f16_t* Wvh  = (f16_t*)(ws + 29360128);
    f16_t* Wph  = (f16_t*)(ws + 31457280);
    f16_t* qh16 = (f16_t*)(ws + 33554432);         // [32][2048][64] f16
    f16_t* kh16 = (f16_t*)(ws + 41943040);
    f16_t* vT   = (f16_t*)(ws + 50331648);         // [32][64][2048] f16
    f16_t* mg   = (f16_t*)(ws + 58720256);         // [4096][1024] f16
    float* qf32 = (float*)(ws + 67108864);         // [32][2048][64] f32
    float* kf32 = (float*)(ws + 83886080);
    float* stats = (float*)(ws + 100663296);       // [32][2048] lgZ
    float2* partials  = (float2*)(ws);             // [32][2048][16] f2 = 8.4 MB (overlays Xq)
    unsigned* dirtymask = (unsigned*)(ws + 16777216 + 4194304);  // inside dead Xv

    prep_kernel<<<dim3(4096, 7), 256, 0, stream>>>(
        (const float4*)queries, (const float4*)keys, (const float4*)values,
        (const float4*)Wq, (const float4*)Wk, (const float4*)Wv, (const float4*)Wp,
        (unsigned short*)Xq, (unsigned short*)Xk, (unsigned short*)Xv,
        (unsigned short*)Wqh, (unsigned short*)Wkh, (unsigned short*)Wvh,
        (unsigned short*)Wph);

    const dim3 gg(8, 32);
    gemm_mfma<0><<<gg, 512, 0, stream>>>(Xq, Wqh, bq, SCL2, qf32, qh16, nullptr);
    gemm_mfma<0><<<gg, 512, 0, stream>>>(Xk, Wkh, bk, 1.0f, kf32, kh16, nullptr);
    gemm_mfma<1><<<gg, 512, 0, stream>>>(Xv, Wvh, bv, 1.0f, nullptr, vT, nullptr);

    attn_zsweep_kernel<<<dim3(16, 32), 512, 0, stream>>>(qh16, kh16, partials);
    zred_kernel<<<dim3(8, 32), 256, 0, stream>>>(partials, stats, dirtymask);
    attn_pv_kernel<<<dim3(32, 32), 256, 0, stream>>>(qh16, kh16, vT, qf32, kf32,
                                                     stats, dirtymask, partials, mg);
    attn_adj_kernel<<<dim3(1024), 256, 0, stream>>>(qh16, kh16, stats, adj);

    gemm_mfma<2><<<gg, 512, 0, stream>>>(mg, Wph, bp, 1.0f, out, nullptr, dirtymask);
}